// Round 8
// baseline (485.767 us; speedup 1.0000x reference)
//
#include <hip/hip_runtime.h>
#include <math.h>
#include <stdint.h>

#define K_CODES 512
#define D_DIM   64
#define TPP     4     // K-split: each of the 4 waves scans 128 contiguous codes
#define PPB     64    // points per block (= lanes; Tp=1 point per lane)

// Constant-address-space pointer: uniform-address loads lower to s_load
// (SMEM/SGPR path), bypassing LDS and the vector memory pipe entirely.
typedef const __attribute__((address_space(4))) float cbf_t;

// FROZEN numerics (bit-exact vs np reference since R3):
//   sz  = numpy AVX512 pairwise tree over individually-rounded squares
//   dot = sequential ascending-i fmaf chain
//   dist= fl( fl(sz - fl(2*dot)) + se ), ascending-k first-min.
__device__ __forceinline__ float np_sumsq64(const float* zarr) {
    float L[16];
#pragma unroll
    for (int j = 0; j < 16; ++j)
        L[j] = __fadd_rn(
            __fadd_rn(__fmul_rn(zarr[j],      zarr[j]),
                      __fmul_rn(zarr[j + 16], zarr[j + 16])),
            __fadd_rn(__fmul_rn(zarr[j + 32], zarr[j + 32]),
                      __fmul_rn(zarr[j + 48], zarr[j + 48])));
    float m[8];
#pragma unroll
    for (int j = 0; j < 8; ++j) m[j] = __fadd_rn(L[j], L[j + 8]);
    float n4[4];
#pragma unroll
    for (int j = 0; j < 4; ++j) n4[j] = __fadd_rn(m[j], m[j + 4]);
    return __fadd_rn(__fadd_rn(n4[0], n4[2]), __fadd_rn(n4[1], n4[3]));
}

__global__ __launch_bounds__(256) void vq_norms_kernel(const float* __restrict__ cb,
                                                       float* __restrict__ norms) {
    int k = blockIdx.x * blockDim.x + threadIdx.x;
    if (k >= K_CODES) return;
    norms[k] = np_sumsq64(cb + (size_t)k * D_DIM);
}

// R8: codebook via the SCALAR pipe. e-values arrive in SGPRs (s_load of
// wave-uniform constant-AS addresses) and feed v_fmac as the one allowed
// SGPR operand; z stays per-lane in VGPRs. The main loop touches neither
// LDS nor per-lane vmem — R5-R7 showed the broadcast-LDS path is pipe-bound
// at ~3x the FMA floor and the allocator spills z under default occupancy
// targeting. amdgpu_waves_per_eu(3,4): max=4 pins the occupancy target so
// the allocator has no incentive to shrink below 128 VGPRs (kills the spill;
// R6/R7 WRITE_SIZE 33 MB = full z scratch round-trip at VGPR=84).
__global__ __launch_bounds__(256)
__attribute__((amdgpu_waves_per_eu(3, 4)))
void vq_argmin_kernel(const float* __restrict__ z, const float* __restrict__ cb,
                      const float* __restrict__ norms, int* __restrict__ out,
                      int n) {
    __shared__ float rv[256];   // (val, idx) cross-wave merge
    __shared__ int   ri[256];

    const int tid  = threadIdx.x;
    const int lane = tid & 63;
    const int q    = tid >> 6;            // wave id 0..3 (wave-uniform)
    const int t    = blockIdx.x * PPB + lane;
    const int tc   = (t < n) ? t : (n - 1);   // clamp load; store is masked

    float zr[D_DIM];
    {
        const float4* zp = reinterpret_cast<const float4*>(z + (size_t)tc * D_DIM);
#pragma unroll
        for (int i = 0; i < 16; ++i) {
            float4 v = zp[i];
            zr[4 * i + 0] = v.x; zr[4 * i + 1] = v.y;
            zr[4 * i + 2] = v.z; zr[4 * i + 3] = v.w;
        }
    }
    const float sz = np_sumsq64(zr);      // FROZEN tree

    cbf_t* cbc = (cbf_t*)(uintptr_t)cb;
    cbf_t* nrc = (cbf_t*)(uintptr_t)norms;

    float best = INFINITY;
    int   bi   = 0;

    const int kbase = q * (K_CODES / TPP);
    for (int k = kbase; k < kbase + K_CODES / TPP; ++k) {
        cbf_t* e = cbc + ((size_t)k << 6);
        float a = 0.f;
#pragma unroll
        for (int i = 0; i < D_DIM; ++i)   // FROZEN: sequential ascending-i
            a = fmaf(zr[i], e[i], a);
        float s = __fadd_rn(__fsub_rn(sz, __fmul_rn(2.0f, a)), nrc[k]);
        if (s < best) { best = s; bi = k; }   // ascending-k first-min
    }

    // Exact cross-wave merge: min value, ties -> lowest index (= first-min).
    rv[tid] = best; ri[tid] = bi;
    __syncthreads();
    if (tid < PPB) {
        float b  = rv[tid];
        int   id = ri[tid];
#pragma unroll
        for (int j = 1; j < TPP; ++j) {
            float v  = rv[tid + j * PPB];
            int   jd = ri[tid + j * PPB];
            if (v < b || (v == b && jd < id)) { b = v; id = jd; }
        }
        const int tt = blockIdx.x * PPB + tid;
        if (tt < n) out[tt] = id;
    }
}

extern "C" void kernel_launch(void* const* d_in, const int* in_sizes, int n_in,
                              void* d_out, int out_size, void* d_ws, size_t ws_size,
                              hipStream_t stream) {
    const float* z  = (const float*)d_in[0];
    const float* cb = (const float*)d_in[1];
    int n = in_sizes[0] / D_DIM;           // 131072 points
    float* norms = (float*)d_ws;           // 512 floats of scratch
    int* out = (int*)d_out;

    vq_norms_kernel<<<(K_CODES + 255) / 256, 256, 0, stream>>>(cb, norms);
    vq_argmin_kernel<<<(n + PPB - 1) / PPB, 256, 0, stream>>>(z, cb, norms, out, n);
}

// Round 9
// 164.002 us; speedup vs baseline: 2.9620x; 2.9620x over previous
//
#include <hip/hip_runtime.h>
#include <math.h>

#define K_CODES 512
#define D_DIM   64
#define CHUNK   128   // codes staged per LDS chunk (32 KB)
#define TPP     4     // K-split: wave q scans 32-code slice of each chunk
#define PPB     128   // points per block = 64 lanes x 2 points/lane

// FROZEN numerics (bit-exact vs np reference since R3):
//   sz  = numpy AVX512 pairwise tree over individually-rounded squares
//   dot = sequential ascending-i fmaf chain
//   dist= fl( fl(sz - fl(2*dot)) + se ), ascending-k first-min.
__device__ __forceinline__ float np_sumsq64(const float* zarr) {
    float L[16];
#pragma unroll
    for (int j = 0; j < 16; ++j)
        L[j] = __fadd_rn(
            __fadd_rn(__fmul_rn(zarr[j],      zarr[j]),
                      __fmul_rn(zarr[j + 16], zarr[j + 16])),
            __fadd_rn(__fmul_rn(zarr[j + 32], zarr[j + 32]),
                      __fmul_rn(zarr[j + 48], zarr[j + 48])));
    float m[8];
#pragma unroll
    for (int j = 0; j < 8; ++j) m[j] = __fadd_rn(L[j], L[j + 8]);
    float n4[4];
#pragma unroll
    for (int j = 0; j < 4; ++j) n4[j] = __fadd_rn(m[j], m[j + 4]);
    return __fadd_rn(__fadd_rn(n4[0], n4[2]), __fadd_rn(n4[1], n4[3]));
}

__global__ __launch_bounds__(256) void vq_norms_kernel(const float* __restrict__ cb,
                                                       float* __restrict__ norms) {
    int k = blockIdx.x * blockDim.x + threadIdx.x;
    if (k >= K_CODES) return;
    norms[k] = np_sumsq64(cb + (size_t)k * D_DIM);
}

// R9 = R6 Tp=2 structure with the spill ACTUALLY fixed.
// R6/R7 spilled because __launch_bounds__(256,3) only sets min waves/EU (a
// VGPR ceiling) — the allocator still chased 6 waves/EU (VGPR=84) and wholesale
// -spilled zA/zB (WRITE_SIZE 33 MB). R8 proved amdgpu_waves_per_eu with max
// pinned controls the allocator. (3,3): VGPR budget 168, zero incentive to
// shrink. Live set ~152: zA+zB 128 + 4 acc + 8 staged e + addressing.
// Why Tp=2: R5/R8 calibration — broadcast ds_read_b128 ~6cyc on the 1 LDS
// pipe/CU vs 4 SIMDs: Tp=1 is LDS-bound 3x FMA floor (R5=168us). Tp=2 halves
// reads/FMA -> ~1.5x floor. Scalar-pipe alternative is dead (R8: 508us).
__global__ __launch_bounds__(256)
__attribute__((amdgpu_waves_per_eu(3, 3)))
void vq_argmin_kernel(const float* __restrict__ z, const float* __restrict__ cb,
                      const float* __restrict__ norms, int* __restrict__ out,
                      int n) {
    __shared__ float4 cb4[CHUNK * 16];    // 32 KB: [row][16 float4]
    __shared__ float4 nrm4[CHUNK / 4];    // 512 B
    __shared__ float  rv[2][256];         // val reduce, A/B
    __shared__ int    ri[2][256];         // idx reduce, A/B
    const float* nrm = (const float*)nrm4;

    const int tid  = threadIdx.x;
    const int lane = tid & 63;
    const int q    = tid >> 6;            // wave quarter 0..3 (wave-uniform)
    const int tA   = blockIdx.x * PPB + lane;
    const int tB   = tA + 64;
    const bool actA = (tA < n), actB = (tB < n);

    float zA[D_DIM], zB[D_DIM];
    if (actA) {
        const float4* zp = reinterpret_cast<const float4*>(z + (size_t)tA * D_DIM);
#pragma unroll
        for (int i = 0; i < 16; ++i) {
            float4 v = zp[i];
            zA[4 * i + 0] = v.x; zA[4 * i + 1] = v.y;
            zA[4 * i + 2] = v.z; zA[4 * i + 3] = v.w;
        }
    } else {
#pragma unroll
        for (int i = 0; i < D_DIM; ++i) zA[i] = 0.f;
    }
    const float szA = np_sumsq64(zA);     // before zB loads: caps live regs

    if (actB) {
        const float4* zp = reinterpret_cast<const float4*>(z + (size_t)tB * D_DIM);
#pragma unroll
        for (int i = 0; i < 16; ++i) {
            float4 v = zp[i];
            zB[4 * i + 0] = v.x; zB[4 * i + 1] = v.y;
            zB[4 * i + 2] = v.z; zB[4 * i + 3] = v.w;
        }
    } else {
#pragma unroll
        for (int i = 0; i < D_DIM; ++i) zB[i] = 0.f;
    }
    const float szB = np_sumsq64(zB);

    float bestA = INFINITY, bestB = INFINITY;
    int   biA   = 0,        biB   = 0;

    for (int c0 = 0; c0 < K_CODES; c0 += CHUNK) {
        __syncthreads();   // previous chunk fully consumed
        {
            // Direct HBM->LDS DMA, 16B/lane, linear dest. No VGPR round-trip.
            const char* gsrc = (const char*)(cb + (size_t)c0 * D_DIM);
            char* lbase = (char*)cb4;
#pragma unroll
            for (int j = 0; j < 8; ++j) {
                size_t off = ((size_t)tid + (size_t)j * 256) * 16;
                __builtin_amdgcn_global_load_lds(
                    (const __attribute__((address_space(1))) void*)(gsrc + off),
                    (__attribute__((address_space(3))) void*)(lbase + off),
                    16, 0, 0);
            }
            if (tid < CHUNK / 4)
                nrm4[tid] = reinterpret_cast<const float4*>(norms + c0)[tid];
        }
        __syncthreads();   // barrier drains vmcnt -> LDS valid

        const int kbase = q * (CHUNK / TPP);               // 32-code slice
        for (int kk = kbase; kk < kbase + CHUNK / TPP; kk += 2) {
            const float4* e0 = cb4 + (kk + 0) * 16;
            const float4* e1 = cb4 + (kk + 1) * 16;
            float a0 = 0.f, a1 = 0.f, b0 = 0.f, b1 = 0.f;
#pragma unroll
            for (int g = 0; g < 16; ++g) {
                float4 v0 = e0[g], v1 = e1[g];
                // element-interleaved across 4 chains; each chain ascending-i
                a0 = fmaf(zA[4 * g + 0], v0.x, a0);
                a1 = fmaf(zA[4 * g + 0], v1.x, a1);
                b0 = fmaf(zB[4 * g + 0], v0.x, b0);
                b1 = fmaf(zB[4 * g + 0], v1.x, b1);
                a0 = fmaf(zA[4 * g + 1], v0.y, a0);
                a1 = fmaf(zA[4 * g + 1], v1.y, a1);
                b0 = fmaf(zB[4 * g + 1], v0.y, b0);
                b1 = fmaf(zB[4 * g + 1], v1.y, b1);
                a0 = fmaf(zA[4 * g + 2], v0.z, a0);
                a1 = fmaf(zA[4 * g + 2], v1.z, a1);
                b0 = fmaf(zB[4 * g + 2], v0.z, b0);
                b1 = fmaf(zB[4 * g + 2], v1.z, b1);
                a0 = fmaf(zA[4 * g + 3], v0.w, a0);
                a1 = fmaf(zA[4 * g + 3], v1.w, a1);
                b0 = fmaf(zB[4 * g + 3], v0.w, b0);
                b1 = fmaf(zB[4 * g + 3], v1.w, b1);
            }
            float nA = nrm[kk + 0], nB = nrm[kk + 1];
            float sA0 = __fadd_rn(__fsub_rn(szA, __fmul_rn(2.0f, a0)), nA);
            float sA1 = __fadd_rn(__fsub_rn(szA, __fmul_rn(2.0f, a1)), nB);
            float sB0 = __fadd_rn(__fsub_rn(szB, __fmul_rn(2.0f, b0)), nA);
            float sB1 = __fadd_rn(__fsub_rn(szB, __fmul_rn(2.0f, b1)), nB);
            if (sA0 < bestA) { bestA = sA0; biA = c0 + kk + 0; }
            if (sA1 < bestA) { bestA = sA1; biA = c0 + kk + 1; }
            if (sB0 < bestB) { bestB = sB0; biB = c0 + kk + 0; }
            if (sB1 < bestB) { bestB = sB1; biB = c0 + kk + 1; }
        }
    }

    // Exact cross-quarter merge: min value, ties -> lowest index (= first-min).
    rv[0][tid] = bestA; ri[0][tid] = biA;
    rv[1][tid] = bestB; ri[1][tid] = biB;
    __syncthreads();
    if (tid < 2 * 64) {
        const int which = tid >> 6;       // 0: point set A, 1: point set B
        const int pl    = tid & 63;
        float best = rv[which][pl];
        int   bi   = ri[which][pl];
#pragma unroll
        for (int j = 1; j < TPP; ++j) {
            float v  = rv[which][j * 64 + pl];
            int   id = ri[which][j * 64 + pl];
            if (v < best || (v == best && id < bi)) { best = v; bi = id; }
        }
        const int t = blockIdx.x * PPB + which * 64 + pl;
        if (t < n) out[t] = bi;
    }
}

extern "C" void kernel_launch(void* const* d_in, const int* in_sizes, int n_in,
                              void* d_out, int out_size, void* d_ws, size_t ws_size,
                              hipStream_t stream) {
    const float* z  = (const float*)d_in[0];
    const float* cb = (const float*)d_in[1];
    int n = in_sizes[0] / D_DIM;           // 131072 points
    float* norms = (float*)d_ws;           // 512 floats of scratch
    int* out = (int*)d_out;

    vq_norms_kernel<<<(K_CODES + 255) / 256, 256, 0, stream>>>(cb, norms);
    vq_argmin_kernel<<<(n + PPB - 1) / PPB, 256, 0, stream>>>(z, cb, norms, out, n);
}

// Round 10
// 118.437 us; speedup vs baseline: 4.1015x; 1.3847x over previous
//
#include <hip/hip_runtime.h>
#include <math.h>

#define K_CODES 512
#define D_DIM   64
#define MT      128    // points per block
#define NT      128    // codes per chunk (4 chunks of 512)
#define DSTR    132    // padded row stride (floats) for transposed LDS tiles
#define THREADS 256

// FROZEN numerics (bit-exact vs np reference since R3):
//   sz  = numpy AVX512 pairwise tree over individually-rounded squares
//   dot = sequential ascending-d fmaf chain per (point,code)
//   dist= fl( fl(sz - fl(2*dot)) + se ), ascending-k first-min.
__device__ __forceinline__ float np_sumsq64_strided(const float* p, int stride) {
    float L[16];
#pragma unroll
    for (int j = 0; j < 16; ++j) {
        float a = p[j * stride],        b = p[(j + 16) * stride];
        float c = p[(j + 32) * stride], d = p[(j + 48) * stride];
        L[j] = __fadd_rn(__fadd_rn(__fmul_rn(a, a), __fmul_rn(b, b)),
                         __fadd_rn(__fmul_rn(c, c), __fmul_rn(d, d)));
    }
    float m[8];
#pragma unroll
    for (int j = 0; j < 8; ++j) m[j] = __fadd_rn(L[j], L[j + 8]);
    float n4[4];
#pragma unroll
    for (int j = 0; j < 4; ++j) n4[j] = __fadd_rn(m[j], m[j + 4]);
    return __fadd_rn(__fadd_rn(n4[0], n4[2]), __fadd_rn(n4[1], n4[3]));
}

__global__ __launch_bounds__(256) void vq_norms_kernel(const float* __restrict__ cb,
                                                       float* __restrict__ norms) {
    int k = blockIdx.x * blockDim.x + threadIdx.x;
    if (k >= K_CODES) return;
    norms[k] = np_sumsq64_strided(cb + (size_t)k * D_DIM, 1);
}

// R10: LDS-tiled GEMM-argmin. R6-R9 lesson: per-thread z arrays (~150 live,
// read-only, long-lived) are the allocator's spill victim at its stubborn
// 128-VGPR budget; attributes don't move it (R9: waves_per_eu(3,3) was a
// bit-identical no-op). So: reuse comes from LDS tiles, registers hold only
// a hot 8x8 accumulator tile (live ~110 < 128 -> no spill motive).
// Per d: 4x ds_read_b128 -> 64 fmaf = 16 FMA/read (R5 was 4) -> VALU-bound.
__global__ __attribute__((amdgpu_flat_work_group_size(256, 256),
                          amdgpu_waves_per_eu(1, 2)))
void vq_argmin_kernel(const float* __restrict__ z, const float* __restrict__ cb,
                      const float* __restrict__ norms, int* __restrict__ out,
                      int n) {
    __shared__ __align__(16) float zT[D_DIM * DSTR];   // 33.8 KB [d][point]
    __shared__ __align__(16) float eT[D_DIM * DSTR];   // 33.8 KB [d][code]
    __shared__ float szL[MT];                          // 512 B
    __shared__ float nrmL[NT];                         // 512 B
    __shared__ float rvL[4][16][8];                    // 2 KB cross-wave merge
    __shared__ int   riL[4][16][8];                    // 2 KB
    // total ~72.7 KB -> 2 blocks/CU (8 waves/CU), VGPR budget >= 128

    const int tid  = threadIdx.x;
    const int mi   = tid & 15;        // point-group  (8 pts each)
    const int ni   = tid >> 4;        // code-group   (8 codes each)
    const int wv   = tid >> 6;        // wave id 0..3
    const int base = blockIdx.x * MT;

    // ---- stage zT (transposed, once per block); coalesced float4 reads ----
    {
        const float4* z4 = reinterpret_cast<const float4*>(z);
#pragma unroll
        for (int rep = 0; rep < 8; ++rep) {
            int flat = rep * THREADS + tid;        // 0..2047
            int pt   = flat >> 4;                  // 0..127
            int dblk = flat & 15;                  // float4 index in row
            int gp   = base + pt; if (gp >= n) gp = n - 1;
            float4 v = z4[(size_t)gp * 16 + dblk];
            zT[(4 * dblk + 0) * DSTR + pt] = v.x;
            zT[(4 * dblk + 1) * DSTR + pt] = v.y;
            zT[(4 * dblk + 2) * DSTR + pt] = v.z;
            zT[(4 * dblk + 3) * DSTR + pt] = v.w;
        }
    }
    __syncthreads();
    // sz per point from zT column (same bits, FROZEN tree)
    if (tid < MT) szL[tid] = np_sumsq64_strided(&zT[tid], DSTR);

    float best[8], bi_f;
    int   bi[8];
#pragma unroll
    for (int r = 0; r < 8; ++r) { best[r] = INFINITY; bi[r] = 0; }
    (void)bi_f;

    const float4* cb4 = reinterpret_cast<const float4*>(cb);
    const float4* nr4 = reinterpret_cast<const float4*>(norms);

    for (int c = 0; c < 4; ++c) {
        __syncthreads();   // prev chunk consumed (also covers zT/szL writes)
        // ---- stage eT (transposed) + norms for codes [c*NT, c*NT+NT) ----
#pragma unroll
        for (int rep = 0; rep < 8; ++rep) {
            int flat = rep * THREADS + tid;
            int code = flat >> 4;
            int dblk = flat & 15;
            float4 v = cb4[(size_t)(c * NT + code) * 16 + dblk];
            eT[(4 * dblk + 0) * DSTR + code] = v.x;
            eT[(4 * dblk + 1) * DSTR + code] = v.y;
            eT[(4 * dblk + 2) * DSTR + code] = v.z;
            eT[(4 * dblk + 3) * DSTR + code] = v.w;
        }
        if (tid < NT / 4)
            reinterpret_cast<float4*>(nrmL)[tid] = nr4[c * (NT / 4) + tid];
        __syncthreads();

        // ---- 8x8 accumulator tile over d=0..63 (FROZEN ascending-d) ----
        float acc[8][8];
#pragma unroll
        for (int r = 0; r < 8; ++r)
#pragma unroll
            for (int j = 0; j < 8; ++j) acc[r][j] = 0.f;

#pragma unroll 4
        for (int d = 0; d < D_DIM; ++d) {
            const float* zrow = &zT[d * DSTR + mi * 8];
            const float* erow = &eT[d * DSTR + ni * 8];
            float4 zf0 = *reinterpret_cast<const float4*>(zrow);
            float4 zf1 = *reinterpret_cast<const float4*>(zrow + 4);
            float4 ef0 = *reinterpret_cast<const float4*>(erow);
            float4 ef1 = *reinterpret_cast<const float4*>(erow + 4);
            float zf[8] = {zf0.x, zf0.y, zf0.z, zf0.w, zf1.x, zf1.y, zf1.z, zf1.w};
            float ef[8] = {ef0.x, ef0.y, ef0.z, ef0.w, ef1.x, ef1.y, ef1.z, ef1.w};
#pragma unroll
            for (int r = 0; r < 8; ++r)
#pragma unroll
                for (int j = 0; j < 8; ++j)
                    acc[r][j] = fmaf(zf[r], ef[j], acc[r][j]);
        }

        // ---- scores + first-min update (codes ascending within thread) ----
#pragma unroll
        for (int r = 0; r < 8; ++r) {
            float szr = szL[mi * 8 + r];
#pragma unroll
            for (int j = 0; j < 8; ++j) {
                float s = __fadd_rn(__fsub_rn(szr, __fmul_rn(2.0f, acc[r][j])),
                                    nrmL[ni * 8 + j]);
                int kidx = c * NT + ni * 8 + j;
                if (s < best[r]) { best[r] = s; bi[r] = kidx; }
            }
        }
    }

    // ---- exact merge: shfl across the wave's 4 ni-subgroups ----
#pragma unroll
    for (int r = 0; r < 8; ++r) {
        float v = best[r]; int id = bi[r];
#pragma unroll
        for (int off = 16; off <= 32; off <<= 1) {
            float ov = __shfl_xor(v, off, 64);
            int   oi = __shfl_xor(id, off, 64);
            if (ov < v || (ov == v && oi < id)) { v = ov; id = oi; }
        }
        if ((tid & 63) < 16) { rvL[wv][mi][r] = v; riL[wv][mi][r] = id; }
    }
    __syncthreads();
    // ---- cross-wave merge + store (ties -> lowest index = first-min) ----
    if (tid < MT) {
        int m = tid, g = m >> 3, r = m & 7;
        float v = rvL[0][g][r]; int id = riL[0][g][r];
#pragma unroll
        for (int w = 1; w < 4; ++w) {
            float ov = rvL[w][g][r]; int oi = riL[w][g][r];
            if (ov < v || (ov == v && oi < id)) { v = ov; id = oi; }
        }
        if (base + m < n) out[base + m] = id;
    }
}

extern "C" void kernel_launch(void* const* d_in, const int* in_sizes, int n_in,
                              void* d_out, int out_size, void* d_ws, size_t ws_size,
                              hipStream_t stream) {
    const float* z  = (const float*)d_in[0];
    const float* cb = (const float*)d_in[1];
    int n = in_sizes[0] / D_DIM;           // 131072 points
    float* norms = (float*)d_ws;           // 512 floats of scratch
    int* out = (int*)d_out;

    vq_norms_kernel<<<(K_CODES + 255) / 256, 256, 0, stream>>>(cb, norms);
    vq_argmin_kernel<<<(n + MT - 1) / MT, THREADS, 0, stream>>>(z, cb, norms, out, n);
}

// Round 11
// 116.937 us; speedup vs baseline: 4.1541x; 1.0128x over previous
//
#include <hip/hip_runtime.h>
#include <math.h>

#define K_CODES 512
#define D_DIM   64
#define BM      128        // points per block (pass 1)
#define NCHUNK  128        // codes per LDS chunk
#define THREADS 256
#define LSTR    72         // padded LDS row stride (ushorts): 64 + 8 -> <=2-way banks
#define EPS_GAP 1e-4f      // certification margin (ref grid noise ~8e-6, 12x safety)

typedef __attribute__((ext_vector_type(8))) short short8v;  // 8 bf16 (4 VGPRs)
typedef __attribute__((ext_vector_type(4))) float f32x4;

// ---------- FROZEN numerics (bit-exact vs np reference since R3) ----------
__device__ __forceinline__ float np_sumsq64(const float* zarr) {
    float L[16];
#pragma unroll
    for (int j = 0; j < 16; ++j)
        L[j] = __fadd_rn(
            __fadd_rn(__fmul_rn(zarr[j],      zarr[j]),
                      __fmul_rn(zarr[j + 16], zarr[j + 16])),
            __fadd_rn(__fmul_rn(zarr[j + 32], zarr[j + 32]),
                      __fmul_rn(zarr[j + 48], zarr[j + 48])));
    float m[8];
#pragma unroll
    for (int j = 0; j < 8; ++j) m[j] = __fadd_rn(L[j], L[j + 8]);
    float n4[4];
#pragma unroll
    for (int j = 0; j < 4; ++j) n4[j] = __fadd_rn(m[j], m[j + 4]);
    return __fadd_rn(__fadd_rn(n4[0], n4[2]), __fadd_rn(n4[1], n4[3]));
}

__global__ __launch_bounds__(256) void vq_norms_kernel(const float* __restrict__ cb,
                                                       float* __restrict__ norms) {
    int k = blockIdx.x * blockDim.x + threadIdx.x;
    if (k >= K_CODES) return;
    float e[D_DIM];
    const float4* p = reinterpret_cast<const float4*>(cb + (size_t)k * D_DIM);
#pragma unroll
    for (int i = 0; i < 16; ++i) {
        float4 v = p[i];
        e[4*i+0]=v.x; e[4*i+1]=v.y; e[4*i+2]=v.z; e[4*i+3]=v.w;
    }
    norms[k] = np_sumsq64(e);
}

// ---------- bf16 split helpers (exact: x = hi + lo + r, |r| <= 2^-18|x|) ----------
__device__ __forceinline__ unsigned short f32_bf16_rne(float x) {
    unsigned int u = __float_as_uint(x);
    unsigned int r = (u + 0x7FFFu + ((u >> 16) & 1u)) >> 16;
    return (unsigned short)r;
}
__device__ __forceinline__ float bf16_f32(unsigned short h) {
    return __uint_as_float(((unsigned int)h) << 16);
}
__device__ __forceinline__ void split2(float x, unsigned short& h, unsigned short& l) {
    h = f32_bf16_rne(x);
    l = f32_bf16_rne(x - bf16_f32(h));   // x - hi is exact in fp32
}

// ---------- Pass 1: MFMA split-bf16 GEMM-argmin with min1/min2 certification ----------
// D = A(e-tile 16x32) * B(z-tile 32x16): C row=(lane>>4)*4+reg = code,
// col=lane&15 = point [m89-verified C/D layout]. A-frag: row=l&15,
// k=(l>>4)*8+{0..7}; B-frag: col=l&15, same k -> both are contiguous 8-bf16
// (one b128) reads from row-major [row][64] LDS tiles. 3 MFMA products
// (hh, hl, lh) x 2 K-halves = 6 MFMA per 16x16 tile; zl*el term ~5e-7, dropped.
__global__ __launch_bounds__(256)
void vq_pass1_kernel(const float* __restrict__ z, const float* __restrict__ cb,
                     const float* __restrict__ norms, int* __restrict__ out, int n) {
    __shared__ unsigned short zhS[BM * LSTR];      // 18 KB each
    __shared__ unsigned short zlS[BM * LSTR];
    __shared__ unsigned short ehS[NCHUNK * LSTR];
    __shared__ unsigned short elS[NCHUNK * LSTR];
    __shared__ float nrmL[NCHUNK];                 // 74.2 KB total -> 2 blocks/CU

    const int tid  = threadIdx.x;
    const int l    = tid & 63;
    const int w    = tid >> 6;        // wave 0..3 -> point-tiles {2w, 2w+1}
    const int j    = l >> 4;          // k-chunk / C-row-group selector 0..3
    const int c16  = l & 15;
    const int base = blockIdx.x * BM;

    // ---- stage z -> hi/lo bf16 (coalesced float4 reads, once per block) ----
    const float4* z4 = reinterpret_cast<const float4*>(z);
#pragma unroll
    for (int rep = 0; rep < 8; ++rep) {
        int flat = rep * THREADS + tid;            // 0..2047
        int pt   = flat >> 4;
        int dblk = flat & 15;
        int gp = base + pt; if (gp >= n) gp = n - 1;
        float4 v = z4[(size_t)gp * 16 + dblk];
        ushort4 h, lo;
        split2(v.x, h.x, lo.x); split2(v.y, h.y, lo.y);
        split2(v.z, h.z, lo.z); split2(v.w, h.w, lo.w);
        *reinterpret_cast<ushort4*>(&zhS[pt * LSTR + dblk * 4]) = h;
        *reinterpret_cast<ushort4*>(&zlS[pt * LSTR + dblk * 4]) = lo;
    }
    __syncthreads();

    // ---- hoist this wave's z (B) fragments: 2 pt-tiles x hi/lo x 2 K-halves ----
    short8v bzh[2][2], bzl[2][2];
#pragma unroll
    for (int p = 0; p < 2; ++p) {
        int pr = ((2 * w + p) * 16 + c16) * LSTR;
#pragma unroll
        for (int h = 0; h < 2; ++h) {
            int off = pr + h * 32 + j * 8;
            bzh[p][h] = *reinterpret_cast<const short8v*>(&zhS[off]);
            bzl[p][h] = *reinterpret_cast<const short8v*>(&zlS[off]);
        }
    }

    float m1[2] = {INFINITY, INFINITY};
    float m2[2] = {INFINITY, INFINITY};
    int   i1[2] = {0, 0};

    for (int c = 0; c < 4; ++c) {
        __syncthreads();   // previous chunk's e-tiles consumed
        const float4* cb4 = reinterpret_cast<const float4*>(cb);
#pragma unroll
        for (int rep = 0; rep < 8; ++rep) {
            int flat = rep * THREADS + tid;
            int code = flat >> 4;
            int dblk = flat & 15;
            float4 v = cb4[(size_t)(c * NCHUNK + code) * 16 + dblk];
            ushort4 h, lo;
            split2(v.x, h.x, lo.x); split2(v.y, h.y, lo.y);
            split2(v.z, h.z, lo.z); split2(v.w, h.w, lo.w);
            *reinterpret_cast<ushort4*>(&ehS[code * LSTR + dblk * 4]) = h;
            *reinterpret_cast<ushort4*>(&elS[code * LSTR + dblk * 4]) = lo;
        }
        if (tid < NCHUNK / 4)
            reinterpret_cast<float4*>(nrmL)[tid] =
                reinterpret_cast<const float4*>(norms)[c * (NCHUNK / 4) + tid];
        __syncthreads();

#pragma unroll
        for (int ct = 0; ct < 8; ++ct) {
            int ar = (ct * 16 + c16) * LSTR + j * 8;
            short8v aeh0 = *reinterpret_cast<const short8v*>(&ehS[ar]);
            short8v aeh1 = *reinterpret_cast<const short8v*>(&ehS[ar + 32]);
            short8v ael0 = *reinterpret_cast<const short8v*>(&elS[ar]);
            short8v ael1 = *reinterpret_cast<const short8v*>(&elS[ar + 32]);
            float4 nr = *reinterpret_cast<const float4*>(&nrmL[ct * 16 + j * 4]);
            float nra[4] = {nr.x, nr.y, nr.z, nr.w};
            int kg0 = c * NCHUNK + ct * 16 + j * 4;
#pragma unroll
            for (int p = 0; p < 2; ++p) {
                f32x4 acc = {0.f, 0.f, 0.f, 0.f};
                acc = __builtin_amdgcn_mfma_f32_16x16x32_bf16(aeh0, bzh[p][0], acc, 0, 0, 0);
                acc = __builtin_amdgcn_mfma_f32_16x16x32_bf16(aeh1, bzh[p][1], acc, 0, 0, 0);
                acc = __builtin_amdgcn_mfma_f32_16x16x32_bf16(aeh0, bzl[p][0], acc, 0, 0, 0);
                acc = __builtin_amdgcn_mfma_f32_16x16x32_bf16(aeh1, bzl[p][1], acc, 0, 0, 0);
                acc = __builtin_amdgcn_mfma_f32_16x16x32_bf16(ael0, bzh[p][0], acc, 0, 0, 0);
                acc = __builtin_amdgcn_mfma_f32_16x16x32_bf16(ael1, bzh[p][1], acc, 0, 0, 0);
#pragma unroll
                for (int r = 0; r < 4; ++r) {
                    float s = fmaf(-2.0f, acc[r], nra[r]);   // accuracy-only path
                    int kg = kg0 + r;
                    bool lt1 = s < m1[p];
                    float nm2 = lt1 ? m1[p] : fminf(s, m2[p]);
                    i1[p] = lt1 ? kg : i1[p];
                    m1[p] = lt1 ? s : m1[p];
                    m2[p] = nm2;
                }
            }
        }
    }

    // ---- butterfly merge across the 4 row-groups (lanes l, l^16, l^32) ----
#pragma unroll
    for (int p = 0; p < 2; ++p) {
        float a1 = m1[p], a2 = m2[p]; int ai = i1[p];
#pragma unroll
        for (int off = 16; off <= 32; off <<= 1) {
            float o1 = __shfl_xor(a1, off, 64);
            float o2 = __shfl_xor(a2, off, 64);
            int   oi = __shfl_xor(ai, off, 64);
            float hi = fmaxf(a1, o1);
            bool take = o1 < a1;                 // ties keep own (tie => flagged anyway)
            ai = take ? oi : ai;
            a1 = take ? o1 : a1;
            a2 = fminf(hi, fminf(a2, o2));
        }
        if (j == 0) {
            int ptg = base + (2 * w + p) * 16 + c16;
            if (ptg < n)
                out[ptg] = ai | ((a2 - a1 <= EPS_GAP) ? (int)0x80000000 : 0);
        }
    }
}

// ---------- Pass 2: wave-cooperative FROZEN rescan of flagged points ----------
__global__ __launch_bounds__(256)
void vq_cleanup_kernel(const float* __restrict__ z, const float* __restrict__ cb,
                       const float* __restrict__ norms, int* __restrict__ out, int n) {
    const int lane  = threadIdx.x & 63;
    const int wid   = blockIdx.x * (blockDim.x >> 6) + (threadIdx.x >> 6);
    const int tbase = wid * 64;
    if (tbase >= n) return;
    int t = tbase + lane;
    int v = (t < n) ? out[t] : 0;
    unsigned long long mask = __ballot(v < 0);
    while (mask) {
        int b = __ffsll(mask) - 1;
        mask &= mask - 1;
        int pt = tbase + b;
        float zr[D_DIM];
        const float4* zp = reinterpret_cast<const float4*>(z + (size_t)pt * D_DIM);
#pragma unroll
        for (int i = 0; i < 16; ++i) {
            float4 q = zp[i];
            zr[4*i+0]=q.x; zr[4*i+1]=q.y; zr[4*i+2]=q.z; zr[4*i+3]=q.w;
        }
        const float sz = np_sumsq64(zr);           // FROZEN tree
        float best = INFINITY; int bi = 0x7FFFFFFF;
#pragma unroll
        for (int r = 0; r < 8; ++r) {
            int k = lane * 8 + r;                  // lane-ordered k => lexicographic OK
            const float* e = cb + ((size_t)k << 6);
            float a = 0.f;
#pragma unroll
            for (int d = 0; d < D_DIM; ++d)        // FROZEN ascending-d chain
                a = fmaf(zr[d], e[d], a);
            float s = __fadd_rn(__fsub_rn(sz, __fmul_rn(2.0f, a)), norms[k]);
            if (s < best) { best = s; bi = k; }
        }
#pragma unroll
        for (int off = 1; off < 64; off <<= 1) {   // (value, index) first-min reduce
            float os = __shfl_xor(best, off, 64);
            int   ok = __shfl_xor(bi, off, 64);
            if (os < best || (os == best && ok < bi)) { best = os; bi = ok; }
        }
        if (lane == 0) out[pt] = bi;
    }
}

extern "C" void kernel_launch(void* const* d_in, const int* in_sizes, int n_in,
                              void* d_out, int out_size, void* d_ws, size_t ws_size,
                              hipStream_t stream) {
    const float* z  = (const float*)d_in[0];
    const float* cb = (const float*)d_in[1];
    int n = in_sizes[0] / D_DIM;           // 131072 points
    float* norms = (float*)d_ws;           // 512 floats of scratch
    int* out = (int*)d_out;

    vq_norms_kernel<<<(K_CODES + 255) / 256, 256, 0, stream>>>(cb, norms);
    vq_pass1_kernel<<<(n + BM - 1) / BM, THREADS, 0, stream>>>(z, cb, norms, out, n);
    vq_cleanup_kernel<<<(n + 255) / 256, 256, 0, stream>>>(z, cb, norms, out, n);
}